// Round 1
// 188.571 us; speedup vs baseline: 1.0805x; 1.0805x over previous
//
#include <hip/hip_runtime.h>
#include <hip/hip_bf16.h>

typedef __attribute__((ext_vector_type(8))) short bf16x8;
typedef __attribute__((ext_vector_type(4))) float f32x4;

#define NB 16
#define C 256
#define HH 56
#define WW 56
#define HW 3136
#define CHW 802816
#define NPIX 50176
#define PH 58
#define PW 58
#define KTOT 2304
#define PPI 3364      // 58*58 padded pixels per image
#define NPIXP 53824   // 16*3364 total padded pixels

#define GLL(g, l) __builtin_amdgcn_global_load_lds( \
    (const __attribute__((address_space(1))) void*)(g), \
    (__attribute__((address_space(3))) void*)(l), 16, 0, 0)

// ---------------- kernel 1: BN stats (fp64 accum, float4 loads, 1024 thr) ----------------
__global__ __launch_bounds__(1024) void stats_kernel(const float* __restrict__ x,
                             const float* __restrict__ gamma, double* __restrict__ stats) {
  int c = blockIdx.x, tid = threadIdx.x;
  double s = 0.0, s2 = 0.0;
  const float* xc = x + (size_t)c * HW;
  for (int k = tid; k < NB * (HW / 4); k += 1024) {   // 12544 float4s
    int n = k / (HW / 4), i = k - n * (HW / 4);
    float4 v = *(const float4*)(xc + (size_t)n * CHW + i * 4);
    double a = v.x, b = v.y, cc = v.z, d = v.w;
    s  += (a + b) + (cc + d);
    s2 += (a * a + b * b) + (cc * cc + d * d);
  }
  __shared__ double rs[1024], rq[1024];
  rs[tid] = s; rq[tid] = s2; __syncthreads();
  for (int o = 512; o > 0; o >>= 1) {
    if (tid < o) { rs[tid] += rs[tid + o]; rq[tid] += rq[tid + o]; }
    __syncthreads();
  }
  if (tid == 0) {
    double mean = rs[0] / (double)NPIX;
    double var = rq[0] / (double)NPIX - mean * mean;
    stats[c] = mean;
    stats[C + c] = (double)gamma[c] / sqrt(var + 1e-4);
  }
}

// ------- kernel 2: ternarize -> padded NHWC (channel-permuted) bf16 Tp + c_sum -------
// channel permutation: slot p = (c&31)*8 + (c>>5)  <->  c = (p&7)*32 + (p>>3)
__global__ __launch_bounds__(256) void ternarize_kernel(const float* __restrict__ x,
                                 const float* __restrict__ beta,
                                 const double* __restrict__ stats,
                                 unsigned short* __restrict__ Tp, float* __restrict__ csum) {
  int bid = blockIdx.x, tid = threadIdx.x;
  int n = bid / HH, h = bid - n * HH;
  __shared__ float xs[256][57];   // stride 57: transposed reads conflict-free
  const float* xb = x + (size_t)n * CHW + h * WW;
#pragma unroll
  for (int j = 0; j < 14; ++j) {
    int idx = j * 256 + tid;
    int c = idx / 14, q = idx - c * 14;
    float4 v = *(const float4*)(xb + (size_t)c * HW + q * 4);
    float* row = &xs[c][q * 4];
    row[0] = v.x; row[1] = v.y; row[2] = v.z; row[3] = v.w;
  }
  int c8 = tid & 31;
  double mu[8], sc[8], bt[8];
#pragma unroll
  for (int e = 0; e < 8; ++e) {
    int c = c8 + 32 * e;
    mu[e] = stats[c]; sc[e] = stats[C + c]; bt[e] = (double)beta[c];
  }
  __syncthreads();
  unsigned short* tb = Tp + ((size_t)(n * PH + h + 1) * PW + 1) * C;
  float* cs = csum + (size_t)(n * PH + h + 1) * PW + 1;
#pragma unroll
  for (int p = 0; p < 7; ++p) {
    int idx = p * 256 + tid;
    int w = idx >> 5;
    unsigned bits[4];
    float msum = 0.f;
#pragma unroll
    for (int e2 = 0; e2 < 4; ++e2) {
      unsigned lo, hi;
      {
        double xn = ((double)xs[c8 + 64 * e2][w] - mu[2 * e2]) * sc[2 * e2] + bt[2 * e2];
        lo = (xn > 0.0) ? 0x3F80u : 0xBF80u;
        msum += (float)fmin(fabs(xn), 1.0);
      }
      {
        double xn = ((double)xs[c8 + 64 * e2 + 32][w] - mu[2 * e2 + 1]) * sc[2 * e2 + 1] + bt[2 * e2 + 1];
        hi = (xn > 0.0) ? 0x3F80u : 0xBF80u;
        msum += (float)fmin(fabs(xn), 1.0);
      }
      bits[e2] = lo | (hi << 16);
    }
    msum += __shfl_xor(msum, 1); msum += __shfl_xor(msum, 2);
    msum += __shfl_xor(msum, 4); msum += __shfl_xor(msum, 8);
    msum += __shfl_xor(msum, 16);
    uint4 v4; v4.x = bits[0]; v4.y = bits[1]; v4.z = bits[2]; v4.w = bits[3];
    *(uint4*)(tb + (size_t)w * C + c8 * 8) = v4;
    if (c8 == 0) cs[w] = msum;
  }
}

// ------- kernel 2b (fused prep): wprep (coalesced-read version) + Tp border zero + csum zero -------
__global__ void prep_kernel(const float* __restrict__ cw, unsigned short* __restrict__ Wp,
                            unsigned short* __restrict__ Tp, float* __restrict__ csum) {
  int b = blockIdx.x, tid = threadIdx.x;
  if (b < 256) {
    // weights OIHW -> [co][tap][perm(c)] bf16 (RNE).
    // Enumerate by INPUT channel: thread tid handles c=tid for co=b,
    // reading 9 contiguous floats (block reads a contiguous 9.2 KB chunk);
    // 2B scatter-writes land inside the co's L2-resident 4.6 KB output block.
    int co = b;
    const float* src = cw + (size_t)co * KTOT;
    unsigned short* dst = Wp + (size_t)co * KTOT;
    float v[9];
#pragma unroll
    for (int t9 = 0; t9 < 9; ++t9) v[t9] = src[tid * 9 + t9];
    int p = (tid & 31) * 8 + (tid >> 5);       // perm slot for channel c=tid
#pragma unroll
    for (int t9 = 0; t9 < 9; ++t9) {
      unsigned u = __builtin_bit_cast(unsigned, v[t9]);
      unsigned lsb = (u >> 16) & 1u;
      u += 0x7FFFu + lsb;
      dst[t9 * 256 + p] = (unsigned short)(u >> 16);
    }
  } else if (b < 712) {
    int g = (b - 256) * 256 + tid;  // 456*256 = 116736 = 16*228*32 exactly
    int n = g / 7296; int r = g - n * 7296;
    int pix = r >> 5, c8 = r & 31;
    int h, w;
    if (pix < 58)      { h = 0;  w = pix; }
    else if (pix < 116){ h = 57; w = pix - 58; }
    else { int rem = pix - 116; h = 1 + (rem >> 1); w = (rem & 1) ? 57 : 0; }
    uint4 z = {0u, 0u, 0u, 0u};
    *(uint4*)(Tp + (size_t)((n * PH + h) * PW + w) * C + c8 * 8) = z;
  } else {
    int i = (b - 712) * 256 + tid;
    if (i < NPIXP) csum[i] = 0.f;
  }
}

// ------- kernel 4: beta_map per pixel -------
__global__ void betamap_kernel(const float* __restrict__ csum, const float* __restrict__ betab,
                               float* __restrict__ bmap) {
  int idx = blockIdx.x * 256 + threadIdx.x;
  if (idx >= NPIX) return;
  int n = idx / HW, r = idx - n * HW;
  int h = r / WW, w = r - h * WW;
  const float* p = csum + (size_t)(n * PH + h) * PW + w;
  float s = 0.f;
  for (int i = 0; i < 3; ++i)
    for (int j = 0; j < 3; ++j) s += p[i * PW + j];
  int rows = 3 - (h == 0) - (h == HH - 1);
  int cols = 3 - (w == 0) - (w == WW - 1);
  float bb = betab[0];
  bmap[idx] = (s + bb) / (256.0f * (float)(rows * cols) + bb);
}

// ------- kernel 5: union-window implicit-GEMM ternary conv -------
// Tile: M=64 co x N=256 padded pixels. Outer loop: c-chunk(8 stages of K=32) ONLY —
// the kh loop is hoisted inside the stage. Per stage we stage:
//   A = As[9tap][64co][32c]  (36,864 B, 9 GLL rounds)
//   B = Bs[384pix][32c]      (24,576 B, 6 GLL rounds) — UNION of the 3 kh windows
//     (was 3x320 staged per kh = 2.2x redundant traffic)
// then run 9 tap positions x 16 MFMA = 144 MFMA between one barrier pair
// (was 48 MFMA per pair, 24 pairs -> now 144 per pair, 8 pairs).
// XOR-on-global-segment permutation unchanged (bank-conflict-free, measured 0).
// LDS = 61,440 B -> 2 blocks/CU; the two blocks anti-phase (one stages while the
// other computes); s_setprio(1) biases the CU scheduler toward the MFMA-phase waves.
__global__ __launch_bounds__(256) void conv_kernel(const unsigned short* __restrict__ Wp,
    const unsigned short* __restrict__ Tp, const float* __restrict__ convb,
    const float* __restrict__ bmap, float* __restrict__ out) {
  int bid = blockIdx.x;
  int ptg = bid >> 5, xcd = bid & 7, ct = (bid >> 3) & 3;
  int pt = ptg * 8 + xcd;                    // pixel tile (same-XCD blocks share it)
  if (pt >= 211) return;
  int tid = threadIdx.x;
  int co0 = ct * 64;

  __shared__ __align__(16) unsigned short As[9 * 64 * 32];   // 36864 B
  __shared__ __align__(16) unsigned short Bs[384 * 32];      // 24576 B

  // ---- A staging plan: 9 GLL rounds, lin = r*256+tid -> [tap9][co][physseg]
  int aofs[9];
#pragma unroll
  for (int r = 0; r < 9; ++r) {
    int lin = r * 256 + tid;
    int co = (lin >> 2) & 63, tap = lin >> 8, pseg = lin & 3;
    int lseg = pseg ^ ((co >> 1) & 3);
    aofs[r] = (co0 + co) * KTOT + tap * 256 + lseg * 8;
  }
  // ---- B staging plan: 6 GLL rounds over union window [pt*256-59, +384)
  int wstart = pt * 256 - 59;
  int bofs[6];
#pragma unroll
  for (int r = 0; r < 6; ++r) {
    int lin = r * 256 + tid;
    int bpix = lin >> 2, pseg = lin & 3;
    int lseg = pseg ^ ((bpix >> 1) & 3);
    int q = wstart + bpix;
    q = q < 0 ? 0 : (q >= NPIXP ? NPIXP - 1 : q);   // clamped rows feed only skipped outputs
    bofs[r] = q * C + lseg * 8;
  }

  int lane = tid & 63, wid = tid >> 6;
  int quad = lane >> 4, row16 = lane & 15;
  int aperm = (quad ^ ((row16 >> 1) & 3)) * 8;
  const unsigned short* aF = As + row16 * 32 + aperm;   // + tap*2048 + mi*512
  int pixb = wid * 64 + row16;                          // staged row = pixb+ni*16+kh*58+kw

  f32x4 acc[4][4];
#pragma unroll
  for (int mi = 0; mi < 4; ++mi)
#pragma unroll
    for (int ni = 0; ni < 4; ++ni)
      acc[mi][ni] = (f32x4){0.f, 0.f, 0.f, 0.f};

  for (int c0 = 0; c0 < 256; c0 += 32) {
    __syncthreads();                       // all waves done reading previous stage
#pragma unroll
    for (int r = 0; r < 9; ++r) GLL(Wp + aofs[r] + c0, As + (r * 256 + tid) * 8);
#pragma unroll
    for (int r = 0; r < 6; ++r) GLL(Tp + bofs[r] + c0, Bs + (r * 256 + tid) * 8);
    __syncthreads();                       // vmcnt(0) drain: stage data visible
    __builtin_amdgcn_s_setprio(1);
#pragma unroll
    for (int kh = 0; kh < 3; ++kh) {
#pragma unroll
      for (int kw = 0; kw < 3; ++kw) {
        int tap = kh * 3 + kw;
        bf16x8 a[4], b[4];
#pragma unroll
        for (int mi = 0; mi < 4; ++mi)
          a[mi] = *(const bf16x8*)(aF + tap * 2048 + mi * 512);
#pragma unroll
        for (int ni = 0; ni < 4; ++ni) {
          int pix = pixb + ni * 16 + kh * 58 + kw;
          b[ni] = *(const bf16x8*)(Bs + pix * 32 + ((quad ^ ((pix >> 1) & 3)) * 8));
        }
#pragma unroll
        for (int mi = 0; mi < 4; ++mi)
#pragma unroll
          for (int ni = 0; ni < 4; ++ni)
            acc[mi][ni] = __builtin_amdgcn_mfma_f32_16x16x32_bf16(a[mi], b[ni], acc[mi][ni], 0, 0, 0);
      }
    }
    __builtin_amdgcn_s_setprio(0);
  }

  // epilogue: out = (acc + conv_b) * beta_map ; skip padded-border/garbage outputs
#pragma unroll
  for (int ni = 0; ni < 4; ++ni) {
    int pp = pt * 256 + wid * 64 + ni * 16 + row16;
    if (pp >= NPIXP) continue;
    int n = pp / PPI; int r = pp - n * PPI;
    int ph = r / PW;  int pw = r - ph * PW;
    if (ph < 1 || ph > 56 || pw < 1 || pw > 56) continue;
    int pix = (ph - 1) * WW + (pw - 1);
    float bm = bmap[n * HW + pix];
    float* ob = out + (size_t)n * CHW + pix;
#pragma unroll
    for (int mi = 0; mi < 4; ++mi) {
      int co = co0 + mi * 16 + quad * 4;
#pragma unroll
      for (int rg = 0; rg < 4; ++rg) {
        ob[(size_t)(co + rg) * HW] = (acc[mi][ni][rg] + convb[co + rg]) * bm;
      }
    }
  }
}

extern "C" void kernel_launch(void* const* d_in, const int* in_sizes, int n_in,
                              void* d_out, int out_size, void* d_ws, size_t ws_size,
                              hipStream_t stream) {
  const float* x     = (const float*)d_in[0];
  const float* gamma = (const float*)d_in[1];
  const float* beta  = (const float*)d_in[2];
  const float* convw = (const float*)d_in[3];
  const float* convb = (const float*)d_in[4];
  const float* betab = (const float*)d_in[5];
  float* out = (float*)d_out;

  char* ws = (char*)d_ws;
  unsigned short* Tp   = (unsigned short*)(ws);                 // 16*58*58*256*2 = 27,557,888
  unsigned short* Wp   = (unsigned short*)(ws + 27557888);      // 256*2304*2     =  1,179,648
  float*          csum = (float*)(ws + 28737536);               // 16*58*58*4     =    215,296
  float*          bmap = (float*)(ws + 28952832);               // 50176*4        =    200,704
  double*         stats= (double*)(ws + 29153536);              // 512*8          =      4,096

  prep_kernel<<<923, 256, 0, stream>>>(convw, Wp, Tp, csum);
  stats_kernel<<<256, 1024, 0, stream>>>(x, gamma, stats);
  ternarize_kernel<<<896, 256, 0, stream>>>(x, beta, stats, Tp, csum);
  betamap_kernel<<<196, 256, 0, stream>>>(csum, betab, bmap);
  conv_kernel<<<864, 256, 0, stream>>>(Wp, Tp, convb, bmap, out);
}